// Round 14
// baseline (138.750 us; speedup 1.0000x reference)
//
#include <hip/hip_runtime.h>
#include <hip/hip_fp16.h>
#include <math.h>

#define NN 100000
#define NE 1600000
#define FIN 50
#define NC 16

#define NSB 64                         // super-buckets (coarse place)
#define SBNODES 1568                   // nodes per super-bucket (8 x 196)
#define SBCAP 26624                    // slots/super-bucket (mean 25000 + 8+ sigma)
#define NPB 196                        // nodes per fine bucket (agg block)
#define NFB 512                        // fine buckets = agg blocks
#define CAP 3584                       // agg slist capacity (mean 3136 + 8 sigma)
#define NBLK_PART 256                  // place blocks (1024 threads)
#define EPB (NE / NBLK_PART)           // 6250 edges/place block (exact)
#define KED ((EPB + 1023) / 1024)      // 7 reg-cached int2 edges/thread
#define NBLK_LIN 256                   // lin blocks (1024 threads)

// ---------------------------------------------------------------------------
// ROUND-13 LESSON: place ~40-44us is THE invariant across 14 rounds; all its
// variants shared 512 fine buckets (512-entry hist/scan, up to 512 global
// cursor atomics/block, 8-16-edge output runs). This round decouples
// placement granularity from aggregation granularity: place into 64 SUPER-
// buckets (runs ~98 edges = 390B coalesced, 64 cursor atomics, one-wave
// scan); agg block f filters its fine bucket (f&7) out of super-bucket f>>3
// (2 L2-warm streaming passes, 1 magic-div compare/edge). blockIdx swizzle
// puts all 8 sharers of a region on one XCD (f = (bx%8)*64 + bx/8) so each
// region is fetched into one L2 once.
// ---------------------------------------------------------------------------
__global__ __launch_bounds__(1024) void fused_front(
    const float* __restrict__ x,
    const float* __restrict__ W_l,
    const float* __restrict__ W_r,
    const int* __restrict__ ei,       // [2, NE]
    int* __restrict__ gcur_s,         // [NSB*16] cursors (zeroed)
    unsigned int* __restrict__ buf,   // [NSB*SBCAP]
    __half* __restrict__ y_l,         // [NN*16]
    float* __restrict__ self_out)     // [NN*NC]
{
    // place: h/lstart/lcur/gbase 4*64*4=1024B | slist 25000B | bid u8 6250B
    //      = 32274B.  lin: zero LDS.
    __shared__ int h[NSB], lstart[NSB], lcur[NSB], gbase[NSB];
    __shared__ unsigned slist[EPB];
    __shared__ unsigned char bid[EPB];
    const int tid = threadIdx.x;
    const int bx  = blockIdx.x;

    if (bx < NBLK_PART) {
        // ---- coarse place role ----
        if (tid < NSB) h[tid] = 0;

        const int e0 = bx * EPB;

        // ei read ONCE into registers (static unroll -> VGPRs, rule #20)
        int2 er[KED];
#pragma unroll
        for (int k = 0; k < KED; ++k) {
            const int e = tid + (k << 10);
            if (e < EPB) { er[k].x = ei[e0 + e]; er[k].y = ei[NE + e0 + e]; }
        }
        __syncthreads();

        // pass 1: 64-entry histogram (s = t/1568, magic-mul div)
#pragma unroll
        for (int k = 0; k < KED; ++k) {
            const int e = tid + (k << 10);
            if (e < EPB) atomicAdd(&h[((unsigned)er[k].y) / 1568u], 1);
        }
        __syncthreads();

        // pass 2: single-wave exclusive scan of h[0..64) + cursor reservation
        if (tid < NSB) {
            const int own = h[tid];
            int incl = own;
#pragma unroll
            for (int off = 1; off < 64; off <<= 1) {
                int t = __shfl_up(incl, off, 64);
                if (tid >= off) incl += t;
            }
            const int st = incl - own;
            lstart[tid] = st;
            lcur[tid]   = st;
            gbase[tid]  = own ? atomicAdd(&gcur_s[tid * 16], own) : 0;
        }
        __syncthreads();

        // pass 3: counting-sort scatter into LDS (64 targets, low contention)
#pragma unroll
        for (int k = 0; k < KED; ++k) {
            const int e = tid + (k << 10);
            if (e < EPB) {
                const unsigned t = (unsigned)er[k].y;
                const unsigned s = t / 1568u;
                const int pos = atomicAdd(&lcur[s], 1);
                slist[pos] = (unsigned)er[k].x | ((t - s * 1568u) << 17);
                bid[pos] = (unsigned char)s;
            }
        }
        __syncthreads();

        // pass 4: coalesced output — runs of ~98 edges (390B) per bucket
        for (int i = tid; i < EPB; i += 1024) {
            const int b = bid[i];
            const int goff = gbase[b] + (i - lstart[b]);
            if (goff < SBCAP)
                buf[(size_t)b * SBCAP + goff] = slist[i];
        }
    } else {
        // ---- lin role: wave-per-node, zero LDS, zero barriers (r11-proven)
        const int lane = tid & 63;
        const int col  = lane & 31;           // output column 0..31
        const int kh   = lane >> 5;           // k-half: 0 -> [0,26), 1 -> [26,50)
        const int nf2  = 13 - kh;             // 13 or 12 float2
        const float* Wrow = ((col < 16) ? (W_l + col * FIN)
                                        : (W_r + (col - 16) * FIN)) + kh * 26;
        float wreg[26];
        {
            const float2* w2 = (const float2*)Wrow;
#pragma unroll
            for (int j = 0; j < 13; ++j)
                if (j < nf2) {
                    float2 t = w2[j];
                    wreg[2 * j]     = t.x;
                    wreg[2 * j + 1] = t.y;
                }
        }
        const int gw = (bx - NBLK_PART) * 16 + (tid >> 6);   // 0..4095
        for (int n = gw; n < NN; n += NBLK_LIN * 16) {
            const float2* x2 = (const float2*)(x + (size_t)n * FIN) + kh * 13;
            float acc = 0.f;
#pragma unroll
            for (int j = 0; j < 13; ++j)
                if (j < nf2) {
                    const float2 t = x2[j];
                    acc = fmaf(t.x, wreg[2 * j], acc);
                    acc = fmaf(t.y, wreg[2 * j + 1], acc);
                }
            acc += __shfl_xor(acc, 32, 64);   // combine the two k-halves
            if (kh == 0) {
                if (col < 16)
                    y_l[(size_t)n * 16 + col] = __float2half(acc);
                else
                    self_out[(size_t)n * NC + (col - 16)] = acc;
            }
        }
    }
}

// ---------------------------------------------------------------------------
// Aggregation: 512 blocks x 1024 threads, fine bucket f = (bx%8)*64 + bx/8
// (XCD co-location: all 8 sharers of super-bucket s = f>>3 have equal bx%8).
// Filter-stream the super-bucket region twice (count, then scatter), in-LDS
// counting sort by node-local id, register segment-reduce, fused epilogue.
// ---------------------------------------------------------------------------
__global__ __launch_bounds__(1024) void agg_kernel(
    const int* __restrict__ gcur_s,
    const unsigned int* __restrict__ buf,
    const uint2* __restrict__ y2,     // y_l as uint2[NN*4]
    const float* __restrict__ b_l,
    float* __restrict__ logp,
    float* __restrict__ outv)         // self (f32) on entry, final out on exit
{
    __shared__ unsigned slist[CAP];   // 14.3 KB
    __shared__ int lcnt[NPB];
    __shared__ int scur[NPB];
    __shared__ int sstart[NPB];
    __shared__ int wsum[4];
    __shared__ float sb[NC];

    const int tid = threadIdx.x;
    const int bx  = blockIdx.x;
    const int f   = (bx & 7) * 64 + (bx >> 3);   // bijective (512 % 8 == 0)
    const int s   = f >> 3;
    const unsigned myf = (unsigned)(f & 7);

    const int tl = tid >> 2;
    const int q  = tid & 3;
    const int n  = f * NPB + tl;

    // EARLY: issue self read; consumed only in the epilogue
    float4 sf = make_float4(0.f, 0.f, 0.f, 0.f);
    if (n < NN && tl < NPB) sf = ((const float4*)(outv + (size_t)n * NC))[q];

    if (tid < NPB) lcnt[tid] = 0;
    if (tid < NC) sb[tid] = b_l[tid];
    __syncthreads();

    int cnt = gcur_s[s * 16];
    if (cnt > SBCAP) cnt = SBCAP;
    const unsigned* region = buf + (size_t)s * SBCAP;

    // pass 1: filtered per-node counts (stream 1 of region, L2-warm shared
    // with the 7 sibling blocks on this XCD)
    for (int i = tid; i < cnt; i += 1024) {
        const unsigned v = region[i];
        const unsigned lt = v >> 17;           // node offset in super-bucket
        const unsigned fl = lt / 196u;
        if (fl == myf) atomicAdd(&lcnt[lt - fl * 196u], 1);
    }
    __syncthreads();

    // pass 2: 196-wide exclusive scan
    int own = 0, incl = 0;
    if (tid < NPB) {
        own = lcnt[tid];
        incl = own;
#pragma unroll
        for (int off = 1; off < 64; off <<= 1) {
            int t = __shfl_up(incl, off, 64);
            if ((tid & 63) >= off) incl += t;
        }
        if ((tid & 63) == 63) wsum[tid >> 6] = incl;
    }
    __syncthreads();
    if (tid < NPB) {
        const int w = tid >> 6;
        int pfx = 0;
        if (w > 0) pfx += wsum[0];
        if (w > 1) pfx += wsum[1];
        if (w > 2) pfx += wsum[2];
        const int st = pfx + incl - own;
        sstart[tid] = st;
        scur[tid]   = st;
    }
    __syncthreads();

    // pass 3: filtered scatter (stream 2 of region, L2-hit)
    for (int i = tid; i < cnt; i += 1024) {
        const unsigned v = region[i];
        const unsigned lt = v >> 17;
        const unsigned fl = lt / 196u;
        if (fl == myf) {
            const int pos = atomicAdd(&scur[lt - fl * 196u], 1);
            if (pos < CAP)
                slist[pos] = v & 0x1FFFF;
        }
    }
    __syncthreads();

    // pass 4: segment reduce, registers only. tid = tl*4 + q; tl < NPB.
    if (tl >= NPB || n >= NN) return;

    const int seg0 = min(sstart[tl], CAP);
    const int deg  = lcnt[tl];
    const int seg1 = min(seg0 + deg, CAP);

    float a0 = 0.f, a1 = 0.f, a2 = 0.f, a3 = 0.f;
    int i = seg0;
    for (; i + 4 <= seg1; i += 4) {
        const int sA = slist[i];
        const int sB = slist[i + 1];
        const int sC = slist[i + 2];
        const int sD = slist[i + 3];
        uint2 qa = y2[sA * 4 + q];
        uint2 qb = y2[sB * 4 + q];
        uint2 qc = y2[sC * 4 + q];
        uint2 qd = y2[sD * 4 + q];
        float2 f0 = __half22float2(__builtin_bit_cast(__half2, qa.x));
        float2 f1 = __half22float2(__builtin_bit_cast(__half2, qa.y));
        float2 f2 = __half22float2(__builtin_bit_cast(__half2, qb.x));
        float2 f3 = __half22float2(__builtin_bit_cast(__half2, qb.y));
        float2 f4 = __half22float2(__builtin_bit_cast(__half2, qc.x));
        float2 f5 = __half22float2(__builtin_bit_cast(__half2, qc.y));
        float2 f6 = __half22float2(__builtin_bit_cast(__half2, qd.x));
        float2 f7 = __half22float2(__builtin_bit_cast(__half2, qd.y));
        a0 += (f0.x + f2.x) + (f4.x + f6.x);
        a1 += (f0.y + f2.y) + (f4.y + f6.y);
        a2 += (f1.x + f3.x) + (f5.x + f7.x);
        a3 += (f1.y + f3.y) + (f5.y + f7.y);
    }
    for (; i < seg1; ++i) {
        uint2 qa = y2[slist[i] * 4 + q];
        float2 f0 = __half22float2(__builtin_bit_cast(__half2, qa.x));
        float2 f1 = __half22float2(__builtin_bit_cast(__half2, qa.y));
        a0 += f0.x; a1 += f0.y; a2 += f1.x; a3 += f1.y;
    }

    // pass 5: fused epilogue, width-4 shfl reductions
    float inv = 1.0f / fmaxf((float)deg, 1.0f);
    float v0 = a0 * inv + sb[4 * q + 0] + sf.x;
    float v1 = a1 * inv + sb[4 * q + 1] + sf.y;
    float v2 = a2 * inv + sb[4 * q + 2] + sf.z;
    float v3 = a3 * inv + sb[4 * q + 3] + sf.w;

    float m = fmaxf(fmaxf(v0, v1), fmaxf(v2, v3));
    m = fmaxf(m, __shfl_xor(m, 1, 4));
    m = fmaxf(m, __shfl_xor(m, 2, 4));
    float es = expf(v0 - m) + expf(v1 - m) + expf(v2 - m) + expf(v3 - m);
    es += __shfl_xor(es, 1, 4);
    es += __shfl_xor(es, 2, 4);
    float lse = m + logf(es);

    ((float4*)(outv + (size_t)n * NC))[q] = make_float4(v0, v1, v2, v3);
    ((float4*)(logp + (size_t)n * NC))[q] =
        make_float4(v0 - lse, v1 - lse, v2 - lse, v3 - lse);
}

extern "C" void kernel_launch(void* const* d_in, const int* in_sizes, int n_in,
                              void* d_out, int out_size, void* d_ws, size_t ws_size,
                              hipStream_t stream) {
    const float* x   = (const float*)d_in[0];
    const int*   ei  = (const int*)d_in[1];
    const float* W_l = (const float*)d_in[2];
    const float* b_l = (const float*)d_in[3];
    const float* W_r = (const float*)d_in[4];

    float* logp = (float*)d_out;                    // [NN*NC]
    float* outv = (float*)d_out + (size_t)NN * NC;  // [NN*NC], self scratch

    // ws: y_l half[NN*16] (3.2MB) | buf u32[NSB*SBCAP] (6.8MB) | gcur (4KB)
    __half* y_l   = (__half*)d_ws;
    unsigned* buf = (unsigned*)(y_l + (size_t)NN * 16);
    int* gcur_s   = (int*)(buf + (size_t)NSB * SBCAP);

    hipMemsetAsync(gcur_s, 0, (size_t)NSB * 16 * sizeof(int), stream);

    fused_front<<<NBLK_PART + NBLK_LIN, 1024, 0, stream>>>(
        x, W_l, W_r, ei, gcur_s, buf, y_l, outv);
    agg_kernel<<<NFB, 1024, 0, stream>>>(gcur_s, buf, (const uint2*)y_l,
                                         b_l, logp, outv);
}

// Round 15
// 123.970 us; speedup vs baseline: 1.1192x; 1.1192x over previous
//
#include <hip/hip_runtime.h>
#include <hip/hip_fp16.h>
#include <math.h>

#define NN 100000
#define NE 1600000
#define FIN 50
#define NC 16

#define NPB 196                       // nodes per bucket
#define NB  512                       // buckets: exactly 2 agg blocks/CU
#define CAP 3584                      // slots/bucket (mean 3136 + 8 sigma)
#define NBLK_PART 256                 // place blocks (1024 threads each)
#define EPB (NE / NBLK_PART)          // 6250 edges/block
#define KED ((EPB + 1023) / 1024)     // 7 register-cached edges/thread
#define NBLK_LIN 256                  // lin blocks (1024 threads each)
#define LTILE 128                     // lin nodes/tile

// ---------------------------------------------------------------------------
// BEST MEASURED KERNEL (r13: 126.16us) — restored after r14's super-bucket
// experiment regressed (138.8). Session findings: budget = harness poison
// fill 44us (fixed) + front ~45 + agg ~30 + gaps ~7. Front's 45us is a
// diffuse cold-cache latency floor: write-amp, atomics, bucket count, LDS
// issue width, and occupancy were each eliminated with zero time delta
// (r0-r14). Front: place (in-LDS counting sort by bucket, ei reg-cached,
// coalesced output) || lin (x@W^T staged in LDS). Agg: 512 blocks = 2/CU
// balanced, reg-cached buf, in-LDS counting sort, register segment-reduce,
// fused mean/bias/self/log_softmax epilogue.
// ---------------------------------------------------------------------------
__global__ __launch_bounds__(1024) void fused_front(
    const float* __restrict__ x,
    const float* __restrict__ W_l,
    const float* __restrict__ W_r,
    const int* __restrict__ ei,       // [2, NE]
    int* __restrict__ gcur_s,         // [NB*16] cursors (zeroed)
    unsigned int* __restrict__ buf,   // [NB*CAP]
    __half2* __restrict__ y_l,        // [NN*8]
    float* __restrict__ self_out)     // [NN*NC]
{
    // place: h/lstart/lcur/gbase 4*512*4=8192B | slist 6250*4=25000B |
    //        bid u16 6250*2=12500B = 45692B.  lin: 32000B (reuses front).
    __shared__ __align__(16) char smem[45696];
    __shared__ int wsum[8];
    const int tid = threadIdx.x;

    if (blockIdx.x < NBLK_PART) {
        // ---- place role ----
        int* h      = (int*)smem;                 // [NB] histogram
        int* lstart = h + NB;                     // [NB] local sorted start
        int* lcur   = lstart + NB;                // [NB] scatter cursor
        int* gbase  = lcur + NB;                  // [NB] global reserved base
        unsigned* slist = (unsigned*)(gbase + NB);            // [EPB]
        unsigned short* bid = (unsigned short*)(slist + EPB); // [EPB]

        if (tid < NB) h[tid] = 0;

        const int e0 = blockIdx.x * EPB;          // EPB divides NE exactly

        // ei read ONCE into registers (static unroll -> VGPRs, rule #20)
        int2 er[KED];
#pragma unroll
        for (int k = 0; k < KED; ++k) {
            const int e = tid + (k << 10);
            if (e < EPB) { er[k].x = ei[e0 + e]; er[k].y = ei[NE + e0 + e]; }
        }
        __syncthreads();

        // pass 1: histogram over buckets (bucket = t/196, magic-mul div)
#pragma unroll
        for (int k = 0; k < KED; ++k) {
            const int e = tid + (k << 10);
            if (e < EPB) atomicAdd(&h[((unsigned)er[k].y) / 196u], 1);
        }
        __syncthreads();

        // pass 2: exclusive scan of h[0..512), thread-per-bucket (8 waves)
        int own = 0, incl = 0;
        if (tid < NB) {
            own = h[tid];
            incl = own;
#pragma unroll
            for (int off = 1; off < 64; off <<= 1) {
                int t = __shfl_up(incl, off, 64);
                if ((tid & 63) >= off) incl += t;
            }
            if ((tid & 63) == 63) wsum[tid >> 6] = incl;
        }
        __syncthreads();
        if (tid < NB) {
            const int w = tid >> 6;
            int pfx = 0;
#pragma unroll
            for (int j = 0; j < 8; ++j)
                if (j < w) pfx += wsum[j];
            const int st = pfx + incl - own;
            lstart[tid] = st;
            lcur[tid]   = st;
            // pass 3 fused: one global cursor reservation per nonempty bucket
            gbase[tid] = own ? atomicAdd(&gcur_s[tid * 16], own) : 0;
        }
        __syncthreads();

        // pass 4: counting-sort scatter into LDS (from registers)
#pragma unroll
        for (int k = 0; k < KED; ++k) {
            const int e = tid + (k << 10);
            if (e < EPB) {
                const unsigned t = (unsigned)er[k].y;
                const unsigned b = t / 196u;
                const int pos = atomicAdd(&lcur[b], 1);
                slist[pos] = (unsigned)er[k].x | ((t - b * 196u) << 17);
                bid[pos] = (unsigned short)b;
            }
        }
        __syncthreads();

        // pass 5: coalesced output — consecutive i => consecutive global
        // addresses within each ~12-edge bucket run
#pragma unroll
        for (int k = 0; k < KED; ++k) {
            const int i = tid + (k << 10);
            if (i < EPB) {
                const unsigned v = slist[i];
                const int b = bid[i];
                const int goff = gbase[b] + (i - lstart[b]);
                if (goff < CAP)
                    buf[(size_t)b * CAP + goff] = v;
            }
        }
    } else {
        // ---- lin role ----
        float* sWl = (float*)smem;            // [NC*FIN]
        float* sWr = sWl + NC * FIN;          // [NC*FIN]
        float* sx  = sWr + NC * FIN;          // [LTILE*FIN]

        if (tid < NC * FIN) {
            sWl[tid] = W_l[tid];
            sWr[tid] = W_r[tid];
        }

        const int bidx = blockIdx.x - NBLK_PART;
        const int ntiles = (NN + LTILE - 1) / LTILE;  // 782 (tail = 32 nodes)
        const int ln = tid >> 3;
        const int cp = tid & 7;

        for (int tile = bidx; tile < ntiles; tile += NBLK_LIN) {
            __syncthreads();
            const int node0 = tile * LTILE;
            const int nn = min(LTILE, NN - node0);
            const int nf4 = nn * FIN / 4;     // exact (nn*50 % 4 == 0)
            {
                const float4* xs = (const float4*)(x + (size_t)node0 * FIN);
                float4* sx4 = (float4*)sx;
                for (int j = tid; j < nf4; j += 1024)
                    sx4[j] = xs[j];
            }
            __syncthreads();

            const int n = node0 + ln;
            if (n >= NN) continue;

            const float* xr = &sx[ln * FIN];
            const float* w0 = &sWl[(2 * cp) * FIN];
            const float* w1 = w0 + FIN;
            const float* u0 = &sWr[(2 * cp) * FIN];
            const float* u1 = u0 + FIN;

            float a0 = 0.f, a1 = 0.f, r0 = 0.f, r1 = 0.f;
#pragma unroll
            for (int k = 0; k < FIN; ++k) {
                float xv = xr[k];
                a0 = fmaf(xv, w0[k], a0);
                a1 = fmaf(xv, w1[k], a1);
                r0 = fmaf(xv, u0[k], r0);
                r1 = fmaf(xv, u1[k], r1);
            }
            y_l[n * 8 + cp] = __floats2half2_rn(a0, a1);
            ((float2*)self_out)[n * 8 + cp] = make_float2(r0, r1);
        }
    }
}

// ---------------------------------------------------------------------------
// Aggregation: 512 blocks x 1024 threads = exactly 2 blocks/CU (LDS 16.8KB,
// VGPR capped 64 via launch_bounds) — balanced single round. buf reg-cached
// (read ONCE). In-LDS counting sort by local target, scan, register
// segment-reduce (tid = tl*4+q, 4-wide unrolled), fused epilogue.
// ---------------------------------------------------------------------------
#define KAGG ((CAP + 1023) / 1024)    // 4 register-cached edges/thread

__global__ __launch_bounds__(1024, 8) void agg_kernel(
    const int* __restrict__ gcur_s,
    const unsigned int* __restrict__ buf,
    const uint2* __restrict__ y2,     // y_l as uint2[NN*4]
    const float* __restrict__ b_l,
    float* __restrict__ logp,
    float* __restrict__ outv)         // self (f32) on entry, final out on exit
{
    __shared__ unsigned slist[CAP];   // 14.3 KB
    __shared__ int lcnt[NPB];
    __shared__ int scur[NPB];
    __shared__ int sstart[NPB];
    __shared__ int wsum[4];
    __shared__ float sb[NC];

    const int tid = threadIdx.x;
    if (tid < NPB) lcnt[tid] = 0;
    if (tid < NC) sb[tid] = b_l[tid];
    __syncthreads();

    const int b = blockIdx.x;
    int cnt = gcur_s[b * 16];
    if (cnt > CAP) cnt = CAP;
    const size_t base = (size_t)b * CAP;

    // register-cache this block's bucket slice: buf read ONCE
    unsigned ev[KAGG];
#pragma unroll
    for (int k = 0; k < KAGG; ++k) {
        const int i = tid + (k << 10);
        if (i < cnt) ev[k] = buf[base + i];
    }

    // pass 1: per-local-node counts (1 LDS int atomic per edge)
#pragma unroll
    for (int k = 0; k < KAGG; ++k) {
        const int i = tid + (k << 10);
        if (i < cnt) atomicAdd(&lcnt[ev[k] >> 17], 1);
    }
    __syncthreads();

    // pass 2: 196-wide exclusive scan (waves 0..3, partial wave 3)
    int own = 0, incl = 0;
    if (tid < NPB) {
        own = lcnt[tid];
        incl = own;
#pragma unroll
        for (int off = 1; off < 64; off <<= 1) {
            int t = __shfl_up(incl, off, 64);
            if ((tid & 63) >= off) incl += t;
        }
        if ((tid & 63) == 63) wsum[tid >> 6] = incl;
    }
    __syncthreads();
    if (tid < NPB) {
        const int w = tid >> 6;
        int pfx = 0;
        if (w > 0) pfx += wsum[0];
        if (w > 1) pfx += wsum[1];
        if (w > 2) pfx += wsum[2];
        const int st = pfx + incl - own;
        sstart[tid] = st;
        scur[tid]   = st;
    }
    __syncthreads();

    // pass 3: scatter src ids into sorted slots (from registers)
#pragma unroll
    for (int k = 0; k < KAGG; ++k) {
        const int i = tid + (k << 10);
        if (i < cnt) {
            const unsigned v = ev[k];
            const int pos = atomicAdd(&scur[v >> 17], 1);
            slist[pos] = v & 0x1FFFF;
        }
    }
    __syncthreads();

    // pass 4: segment reduce, registers only. tid = tl*4 + q; tl < NPB.
    const int tl = tid >> 2;
    const int q  = tid & 3;
    if (tl >= NPB) return;
    const int n  = b * NPB + tl;
    if (n >= NN) return;

    const int seg0 = sstart[tl];
    const int deg  = lcnt[tl];
    const int seg1 = seg0 + deg;

    float a0 = 0.f, a1 = 0.f, a2 = 0.f, a3 = 0.f;
    int i = seg0;
    for (; i + 4 <= seg1; i += 4) {
        const int sA = slist[i];
        const int sB = slist[i + 1];
        const int sC = slist[i + 2];
        const int sD = slist[i + 3];
        uint2 qa = y2[sA * 4 + q];
        uint2 qb = y2[sB * 4 + q];
        uint2 qc = y2[sC * 4 + q];
        uint2 qd = y2[sD * 4 + q];
        float2 f0 = __half22float2(__builtin_bit_cast(__half2, qa.x));
        float2 f1 = __half22float2(__builtin_bit_cast(__half2, qa.y));
        float2 f2 = __half22float2(__builtin_bit_cast(__half2, qb.x));
        float2 f3 = __half22float2(__builtin_bit_cast(__half2, qb.y));
        float2 f4 = __half22float2(__builtin_bit_cast(__half2, qc.x));
        float2 f5 = __half22float2(__builtin_bit_cast(__half2, qc.y));
        float2 f6 = __half22float2(__builtin_bit_cast(__half2, qd.x));
        float2 f7 = __half22float2(__builtin_bit_cast(__half2, qd.y));
        a0 += (f0.x + f2.x) + (f4.x + f6.x);
        a1 += (f0.y + f2.y) + (f4.y + f6.y);
        a2 += (f1.x + f3.x) + (f5.x + f7.x);
        a3 += (f1.y + f3.y) + (f5.y + f7.y);
    }
    for (; i < seg1; ++i) {
        uint2 qa = y2[slist[i] * 4 + q];
        float2 f0 = __half22float2(__builtin_bit_cast(__half2, qa.x));
        float2 f1 = __half22float2(__builtin_bit_cast(__half2, qa.y));
        a0 += f0.x; a1 += f0.y; a2 += f1.x; a3 += f1.y;
    }

    // pass 5: fused epilogue, width-4 shfl reductions
    const float4 sf = ((const float4*)(outv + (size_t)n * NC))[q];
    float inv = 1.0f / fmaxf((float)deg, 1.0f);
    float v0 = a0 * inv + sb[4 * q + 0] + sf.x;
    float v1 = a1 * inv + sb[4 * q + 1] + sf.y;
    float v2 = a2 * inv + sb[4 * q + 2] + sf.z;
    float v3 = a3 * inv + sb[4 * q + 3] + sf.w;

    float m = fmaxf(fmaxf(v0, v1), fmaxf(v2, v3));
    m = fmaxf(m, __shfl_xor(m, 1, 4));
    m = fmaxf(m, __shfl_xor(m, 2, 4));
    float es = expf(v0 - m) + expf(v1 - m) + expf(v2 - m) + expf(v3 - m);
    es += __shfl_xor(es, 1, 4);
    es += __shfl_xor(es, 2, 4);
    float lse = m + logf(es);

    ((float4*)(outv + (size_t)n * NC))[q] = make_float4(v0, v1, v2, v3);
    ((float4*)(logp + (size_t)n * NC))[q] =
        make_float4(v0 - lse, v1 - lse, v2 - lse, v3 - lse);
}

extern "C" void kernel_launch(void* const* d_in, const int* in_sizes, int n_in,
                              void* d_out, int out_size, void* d_ws, size_t ws_size,
                              hipStream_t stream) {
    const float* x   = (const float*)d_in[0];
    const int*   ei  = (const int*)d_in[1];
    const float* W_l = (const float*)d_in[2];
    const float* b_l = (const float*)d_in[3];
    const float* W_r = (const float*)d_in[4];

    float* logp = (float*)d_out;                    // [NN*NC]
    float* outv = (float*)d_out + (size_t)NN * NC;  // [NN*NC], self scratch

    // ws: y_l half2[NN*8] (3.2MB) | buf u32[NB*CAP] (7.3MB) | gcur_s[NB*16]
    __half2* y_l  = (__half2*)d_ws;
    unsigned* buf = (unsigned*)(y_l + (size_t)NN * 8);
    int* gcur_s   = (int*)(buf + (size_t)NB * CAP);

    hipMemsetAsync(gcur_s, 0, (size_t)NB * 16 * sizeof(int), stream);

    fused_front<<<NBLK_PART + NBLK_LIN, 1024, 0, stream>>>(
        x, W_l, W_r, ei, gcur_s, buf, y_l, outv);
    agg_kernel<<<NB, 1024, 0, stream>>>(gcur_s, buf, (const uint2*)y_l, b_l, logp, outv);
}